// Round 13
// baseline (269.038 us; speedup 1.0000x reference)
//
#include <hip/hip_runtime.h>
#include <hip/hip_bf16.h>

#define SEQ   2048
#define NH    16
#define DK    64
#define DM    1024
#define NTOK  4096
#define C1    0.1803368801111204f   // 0.125 * log2(e)

typedef unsigned short u16;
typedef unsigned int   u32;
typedef short bhalf8 __attribute__((ext_vector_type(8)));   // 8 bf16 = 4 VGPRs
typedef short bhalf4 __attribute__((ext_vector_type(4)));   // 4 bf16 = 2 VGPRs
typedef float floatx4 __attribute__((ext_vector_type(4)));  // MFMA acc

#define MFMA16(a,b,c) __builtin_amdgcn_mfma_f32_16x16x32_bf16(a,b,c,0,0,0)
#define MFMA4(a,b,c)  __builtin_amdgcn_mfma_f32_16x16x16bf16_1k(a,b,c,0,0,0)

#if __has_builtin(__builtin_amdgcn_exp2f)
#define EXP2(x) __builtin_amdgcn_exp2f(x)
#else
#define EXP2(x) exp2f(x)
#endif

__device__ __forceinline__ u16 f2b(float f){
  union { float f; u32 u; } v; v.f = f;
  u32 r = v.u + 0x7fffu + ((v.u >> 16) & 1u);
  return (u16)(r >> 16);
}
__device__ __forceinline__ u32 pk2(float a, float b){
  union { __hip_bfloat162 h; u32 w; } o;
  o.h = __float22bfloat162_rn(make_float2(a, b));
  return o.w;
}
// async global->LDS, 16B/lane; lds ptr must be wave-uniform (HW adds lane*16)
__device__ __forceinline__ void gld_lds16(const u16* g, u16* lds){
  __builtin_amdgcn_global_load_lds(
      (const __attribute__((address_space(1))) u32*)g,
      (__attribute__((address_space(3))) u32*)lds, 16, 0, 0);
}

// ---------------------------------------------------------------------------
// Fused fp32->bf16 convert for q,k,v (memory-bound), 8 elems/thread
// ---------------------------------------------------------------------------
__global__ __launch_bounds__(256)
void cvt_qkv(const float* __restrict__ q, const float* __restrict__ k,
             const float* __restrict__ v, u16* __restrict__ Aq,
             u16* __restrict__ Ak, u16* __restrict__ Av)
{
  const float* in = (blockIdx.y == 0) ? q : (blockIdx.y == 1) ? k : v;
  u16* out       = (blockIdx.y == 0) ? Aq : (blockIdx.y == 1) ? Ak : Av;
  const size_t i = ((size_t)blockIdx.x * 256 + threadIdx.x) * 8;
  const float4 a = *(const float4*)(in + i);
  const float4 b = *(const float4*)(in + i + 4);
  uint4 o;
  o.x = pk2(a.x, a.y); o.y = pk2(a.z, a.w);
  o.z = pk2(b.x, b.y); o.w = pk2(b.z, b.w);
  *(uint4*)(out + i) = o;
}

// ---------------------------------------------------------------------------
// Fused transpose+convert: 4 weights fp32 [k][n] -> Wtall bf16 [z][n][k]
// ---------------------------------------------------------------------------
__global__ __launch_bounds__(256)
void wtrans4(const float* __restrict__ Wq, const float* __restrict__ Wk,
             const float* __restrict__ Wv, const float* __restrict__ Wo,
             u16* __restrict__ Wtall)
{
  __shared__ __align__(16) u16 T[64][68];
  const int z = blockIdx.z;
  const float* W = (z == 0) ? Wq : (z == 1) ? Wk : (z == 2) ? Wv : Wo;
  u16* Wt = Wtall + (size_t)z * DM * DM;
  const int k0 = blockIdx.y * 64, n0 = blockIdx.x * 64;
  const int t = threadIdx.x;
  #pragma unroll
  for (int p = 0; p < 16; ++p){
    int e = p*256 + t, k = e >> 6, n = e & 63;
    T[n][k] = f2b(W[(size_t)(k0+k)*DM + n0 + n]);
  }
  __syncthreads();
  #pragma unroll
  for (int p = 0; p < 8; ++p){
    int e = p*256 + t, n = e >> 5, kp = e & 31;
    u32 val = *(const u32*)&T[n][2*kp];
    *(u32*)&Wt[(size_t)(n0+n)*DM + k0 + 2*kp] = val;
  }
}

// ---------------------------------------------------------------------------
// Fused Q/K/V projection GEMM (m97 tile + XOR-swizzled LDS + 2-phase
// double-buffer: prefetch kc+32 issued before compute of kc, 1 barrier/iter).
// grid (DM/128, NTOK/128, 3); z picks A/W/bias/output.
// z=0: Qb = (q W + b)*C1 ; z=1: Kb ; z=2: Vt[((b*NH+h)*DK+d)*SEQ+s] (no scale)
// ---------------------------------------------------------------------------
__global__ __launch_bounds__(256)
void gemm_qkv(const u16* __restrict__ Aq, const u16* __restrict__ Ak,
              const u16* __restrict__ Av, const u16* __restrict__ Wtall,
              const float* __restrict__ bq, const float* __restrict__ bk,
              const float* __restrict__ bv, u16* __restrict__ Qb,
              u16* __restrict__ Kb, u16* __restrict__ Vt)
{
  __shared__ __align__(16) u16 Asm[2][128*32];   // [buf] rows of 64B, swizzled
  __shared__ __align__(16) u16 Bsm[2][128*32];
  const int z = blockIdx.z;
  const u16* A = (z == 0) ? Aq : (z == 1) ? Ak : Av;
  const u16* Wt = Wtall + (size_t)z * DM * DM;
  const float* bias = (z == 0) ? bq : (z == 1) ? bk : bv;
  const float cmul = (z == 0) ? C1 : 1.0f;

  const int bm = blockIdx.y * 128, bn = blockIdx.x * 128;
  const int t = threadIdx.x, wid = t >> 6, l = t & 63, r16 = l & 15, q = l >> 4;
  const int wm = (wid & 1) * 64, wn = (wid >> 1) * 64;
  // staging: lds slot = t (16B units); row = t>>2, slot-chunk = t&3,
  // global chunk g = (t&3) ^ (row&3)  (XOR swizzle)
  const int rL = t >> 2, gL = ((t & 3) ^ (rL & 3)) * 8;
  const u16* Ag = A  + (size_t)(bm + rL)*DM + gL;
  const u16* Bg = Wt + (size_t)(bn + rL)*DM + gL;
  const int wo = wid*512;
  const int sw = (r16 & 3);   // frag-read swizzle key
  floatx4 acc[4][4] = {};

  // prologue: stage kc=0 into buffer 0
  gld_lds16(Ag,                  Asm[0] + wo);
  gld_lds16(Ag + (size_t)64*DM,  Asm[0] + wo + 2048);
  gld_lds16(Bg,                  Bsm[0] + wo);
  gld_lds16(Bg + (size_t)64*DM,  Bsm[0] + wo + 2048);
  __syncthreads();

  int cur = 0;
  for (int kc = 0; kc < DM; kc += 32){
    if (kc + 32 < DM){
      const int nx = cur ^ 1;
      gld_lds16(Ag + kc + 32,                 Asm[nx] + wo);
      gld_lds16(Ag + kc + 32 + (size_t)64*DM, Asm[nx] + wo + 2048);
      gld_lds16(Bg + kc + 32,                 Bsm[nx] + wo);
      gld_lds16(Bg + kc + 32 + (size_t)64*DM, Bsm[nx] + wo + 2048);
    }
    __builtin_amdgcn_s_setprio(1);
    bhalf8 af[4], bf[4];
    #pragma unroll
    for (int i = 0; i < 4; ++i)
      af[i] = *(const bhalf8*)&Asm[cur][(wm + i*16 + r16)*32 + ((q ^ sw)*8)];
    #pragma unroll
    for (int j = 0; j < 4; ++j)
      bf[j] = *(const bhalf8*)&Bsm[cur][(wn + j*16 + r16)*32 + ((q ^ sw)*8)];
    #pragma unroll
    for (int i = 0; i < 4; ++i)
      #pragma unroll
      for (int j = 0; j < 4; ++j)
        acc[i][j] = MFMA16(af[i], bf[j], acc[i][j]);
    __builtin_amdgcn_s_setprio(0);
    __syncthreads();   // drains vmcnt: next buffer staged; frag reads done
    cur ^= 1;
  }

  if (z < 2){
    u16* C = (z == 0) ? Qb : Kb;
    #pragma unroll
    for (int j = 0; j < 4; ++j){
      const int n = bn + wn + j*16 + r16;
      const float bj = bias[n];
      #pragma unroll
      for (int i = 0; i < 4; ++i){
        const int m0 = bm + wm + i*16 + q*4;
        #pragma unroll
        for (int r = 0; r < 4; ++r)
          C[(size_t)(m0+r)*DM + n] = f2b((acc[i][j][r] + bj) * cmul);
      }
    }
  } else {
    const int h  = (bn + wn) >> 6;
    const int bb = (bm + wm) >> 11;
    const int s0 = (bm + wm) & (SEQ - 1);
    #pragma unroll
    for (int i = 0; i < 4; ++i){
      const int sl = s0 + i*16 + q*4;
      #pragma unroll
      for (int j = 0; j < 4; ++j){
        const int d = j*16 + r16;
        const float bj = bias[h*DK + d];
        u32 v0 = pk2(acc[i][j][0]+bj, acc[i][j][1]+bj);
        u32 v1 = pk2(acc[i][j][2]+bj, acc[i][j][3]+bj);
        *(uint2*)&Vt[((size_t)(bb*NH + h)*DK + d)*SEQ + sl] = make_uint2(v0, v1);
      }
    }
  }
}

// ---------------------------------------------------------------------------
// O-projection GEMM (same 2-phase double-buffered structure), bf16 -> fp32
// ---------------------------------------------------------------------------
__global__ __launch_bounds__(256)
void gemm_o(const u16* __restrict__ A, const u16* __restrict__ Wt,
            const float* __restrict__ bias, float* __restrict__ C)
{
  __shared__ __align__(16) u16 Asm[2][128*32];
  __shared__ __align__(16) u16 Bsm[2][128*32];
  const int bm = blockIdx.y * 128, bn = blockIdx.x * 128;
  const int t = threadIdx.x, wid = t >> 6, l = t & 63, r16 = l & 15, q = l >> 4;
  const int wm = (wid & 1) * 64, wn = (wid >> 1) * 64;
  const int rL = t >> 2, gL = ((t & 3) ^ (rL & 3)) * 8;
  const u16* Ag = A  + (size_t)(bm + rL)*DM + gL;
  const u16* Bg = Wt + (size_t)(bn + rL)*DM + gL;
  const int wo = wid*512;
  const int sw = (r16 & 3);
  floatx4 acc[4][4] = {};

  gld_lds16(Ag,                  Asm[0] + wo);
  gld_lds16(Ag + (size_t)64*DM,  Asm[0] + wo + 2048);
  gld_lds16(Bg,                  Bsm[0] + wo);
  gld_lds16(Bg + (size_t)64*DM,  Bsm[0] + wo + 2048);
  __syncthreads();

  int cur = 0;
  for (int kc = 0; kc < DM; kc += 32){
    if (kc + 32 < DM){
      const int nx = cur ^ 1;
      gld_lds16(Ag + kc + 32,                 Asm[nx] + wo);
      gld_lds16(Ag + kc + 32 + (size_t)64*DM, Asm[nx] + wo + 2048);
      gld_lds16(Bg + kc + 32,                 Bsm[nx] + wo);
      gld_lds16(Bg + kc + 32 + (size_t)64*DM, Bsm[nx] + wo + 2048);
    }
    __builtin_amdgcn_s_setprio(1);
    bhalf8 af[4], bf[4];
    #pragma unroll
    for (int i = 0; i < 4; ++i)
      af[i] = *(const bhalf8*)&Asm[cur][(wm + i*16 + r16)*32 + ((q ^ sw)*8)];
    #pragma unroll
    for (int j = 0; j < 4; ++j)
      bf[j] = *(const bhalf8*)&Bsm[cur][(wn + j*16 + r16)*32 + ((q ^ sw)*8)];
    #pragma unroll
    for (int i = 0; i < 4; ++i)
      #pragma unroll
      for (int j = 0; j < 4; ++j)
        acc[i][j] = MFMA16(af[i], bf[j], acc[i][j]);
    __builtin_amdgcn_s_setprio(0);
    __syncthreads();
    cur ^= 1;
  }
  #pragma unroll
  for (int j = 0; j < 4; ++j){
    const int n = bn + wn + j*16 + r16;
    const float bj = bias[n];
    #pragma unroll
    for (int i = 0; i < 4; ++i){
      const int m0 = bm + wm + i*16 + q*4;
      #pragma unroll
      for (int r = 0; r < 4; ++r)
        C[(size_t)(m0+r)*DM + n] = acc[i][j][r] + bj;
    }
  }
}

// ---------------------------------------------------------------------------
// Stats + fold: compute l_j = sum_i 2^(s'_ij) for its 64 j's, then scale
// Vt[bh][d][j] *= 1/l_j in place. Linv never touches global.
// ---------------------------------------------------------------------------
__global__ __launch_bounds__(256)
void attn_stats(const u16* __restrict__ Qb, const u16* __restrict__ Kb,
                u16* __restrict__ Vt)
{
  __shared__ float pl[4][64];
  __shared__ float sLinv[64];
  const int j0 = blockIdx.x * 64, bh = blockIdx.y, b = bh >> 4, h = bh & 15;
  const int t = threadIdx.x, wid = t >> 6, l = t & 63, r16 = l & 15, q = l >> 4;

  bhalf8 kf[4][2];
  const u16* kp = Kb + (size_t)(b*SEQ + j0 + r16)*DM + h*DK + q*8;
  #pragma unroll
  for (int st = 0; st < 4; ++st){
    kf[st][0] = *(const bhalf8*)(kp + (size_t)st*16*DM);
    kf[st][1] = *(const bhalf8*)(kp + (size_t)st*16*DM + 32);
  }
  float rl[4] = {0.f, 0.f, 0.f, 0.f};
  const u16* qp = Qb + (size_t)(b*SEQ + wid*16 + r16)*DM + h*DK + q*8;
  for (int it = 0; it < SEQ/64; ++it){
    bhalf8 qf0 = *(const bhalf8*)qp;
    bhalf8 qf1 = *(const bhalf8*)(qp + 32);
    qp += (size_t)64*DM;
    #pragma unroll
    for (int st = 0; st < 4; ++st){
      floatx4 s = {};
      s = MFMA16(qf0, kf[st][0], s);
      s = MFMA16(qf1, kf[st][1], s);
      rl[st] += EXP2(s[0]) + EXP2(s[1]) + EXP2(s[2]) + EXP2(s[3]);
    }
  }
  #pragma unroll
  for (int st = 0; st < 4; ++st){
    float v = rl[st];
    v += __shfl_xor(v, 16);
    v += __shfl_xor(v, 32);
    rl[st] = v;
  }
  if (q == 0){
    #pragma unroll
    for (int st = 0; st < 4; ++st) pl[wid][st*16 + r16] = rl[st];
  }
  __syncthreads();
  if (t < 64)
    sLinv[t] = 1.f / (pl[0][t] + pl[1][t] + pl[2][t] + pl[3][t]);
  __syncthreads();
  // scale Vt[bh][d][j0..j0+63] by sLinv[j-j0]; 16 elems/thread
  {
    const int d = t >> 2, cb = (t & 3) * 16;
    u16* vp = Vt + ((size_t)bh*DK + d)*SEQ + j0 + cb;
    uint4 w0 = *(uint4*)vp, w1 = *(uint4*)(vp + 8);
    float sc[16];
    #pragma unroll
    for (int e = 0; e < 16; ++e) sc[e] = sLinv[cb + e];
    #define SC2(w, s0, s1) pk2(__uint_as_float((w) << 16) * (s0), \
                               __uint_as_float((w) & 0xffff0000u) * (s1))
    w0.x = SC2(w0.x, sc[0],  sc[1]);  w0.y = SC2(w0.y, sc[2],  sc[3]);
    w0.z = SC2(w0.z, sc[4],  sc[5]);  w0.w = SC2(w0.w, sc[6],  sc[7]);
    w1.x = SC2(w1.x, sc[8],  sc[9]);  w1.y = SC2(w1.y, sc[10], sc[11]);
    w1.z = SC2(w1.z, sc[12], sc[13]); w1.w = SC2(w1.w, sc[14], sc[15]);
    #undef SC2
    *(uint4*)vp = w0; *(uint4*)(vp + 8) = w1;
  }
}

// ---------------------------------------------------------------------------
// PV: X[i][d] = sum_j 2^(s'_ij) * V'[j][d]  (V' pre-scaled by 1/l_j)
// i-tile 128 (wave = 32 i as 2 groups). K/V double-buffered in LDS.
// P stays IN REGISTERS: QK^T is computed as S^T (D[j][i]; lane q,r16 holds
// j=st*16+q*4+r, i=r16), whose C-layout exactly matches the B-operand layout
// of the K=16 MFMA (k=(l>>4)*4+e). PV is computed transposed:
// X^T[d][i] = sum V'^T[d][j] P^T[j][i], A = V^T fragments from Vls (b64),
// B = exp2-packed bhalf4 straight from the accumulator. No Pls, no lgkm
// round-trip; epilogue becomes 8x 8B vectorized stores.
// ---------------------------------------------------------------------------
__global__ __launch_bounds__(256)
void attn_pv(const u16* __restrict__ Qb, const u16* __restrict__ Kb,
             const u16* __restrict__ Vt, u16* __restrict__ Xb)
{
  __shared__ __align__(16) u16 Kls[2][64*64];    // [buf][j][d], swizzled
  __shared__ __align__(16) u16 Vls[2][64*64];    // [buf][d][s], swizzled
  const int i0 = blockIdx.x * 128, bh = blockIdx.y, b = bh >> 4, h = bh & 15;
  const int t = threadIdx.x, wid = t >> 6, l = t & 63, r16 = l & 15, q = l >> 4;

  // Q fragments: wave's 32 i-rows as 2 groups of 16 (direct global)
  bhalf8 qf[2][2];
  #pragma unroll
  for (int g = 0; g < 2; ++g){
    const u16* qp = Qb + (size_t)(b*SEQ + i0 + wid*32 + g*16 + r16)*DM + h*DK + q*8;
    qf[g][0] = *(const bhalf8*)qp;
    qf[g][1] = *(const bhalf8*)(qp + 32);
  }

  // gld staging: slot = call*256 + t; row = slot>>3, chunk c = slot&7,
  // global chunk g = c ^ (row&7)
  const int row0 = t >> 3, c0 = t & 7;
  const int g0 = (c0 ^ (row0 & 7)) * 8;
  const int row1 = row0 + 32;
  const int g1 = (c0 ^ (row1 & 7)) * 8;
  const u16* kp0 = Kb + (size_t)(b*SEQ + row0)*DM + h*DK + g0;
  const u16* kp1 = Kb + (size_t)(b*SEQ + row1)*DM + h*DK + g1;
  const u16* vp0 = Vt + ((size_t)bh*DK + row0)*SEQ + g0;
  const u16* vp1 = Vt + ((size_t)bh*DK + row1)*SEQ + g1;
  const int wo = wid*512;
  const int sw = (r16 & 7);   // frag-read swizzle key

  floatx4 xaccT[2][4] = {};   // [g][dst]: X^T[d=dst*16+q*4+r][i=r16]

  // prologue: stage jt=0 into buffer 0
  gld_lds16(kp0, &Kls[0][wo]);
  gld_lds16(kp1, &Kls[0][wo + 2048]);
  gld_lds16(vp0, &Vls[0][wo]);
  gld_lds16(vp1, &Vls[0][wo + 2048]);
  __syncthreads();

  int cur = 0;
  for (int jt = 0; jt < SEQ/64; ++jt){
    // prefetch jt+1 into the other buffer; latency hidden under compute.
    if (jt + 1 < SEQ/64){
      const int nx = cur ^ 1;
      gld_lds16(kp0 + (size_t)(jt+1)*64*DM, &Kls[nx][wo]);
      gld_lds16(kp1 + (size_t)(jt+1)*64*DM, &Kls[nx][wo + 2048]);
      gld_lds16(vp0 + (jt+1)*64,            &Vls[nx][wo]);
      gld_lds16(vp1 + (jt+1)*64,            &Vls[nx][wo + 2048]);
    }
    const u16* Kc = &Kls[cur][0];
    const u16* Vc = &Vls[cur][0];

    __builtin_amdgcn_s_setprio(1);
    // S^T: A=K (j rows), B=Q (i cols) -> D[j][i]; lane (q,r16) holds
    // s[r] = S[j=st*16+q*4+r][i=r16]. exp2+pack -> bhalf4 = B-operand of
    // the K=16 PV MFMA (k=(l>>4)*4+e matches C-layout row=(l>>4)*4+r).
    bhalf4 pb[4][2];
    #pragma unroll
    for (int st = 0; st < 4; ++st){
      const int kr = (st*16 + r16) * 64;
      bhalf8 k0 = *(const bhalf8*)&Kc[kr + ((q     ^ sw) * 8)];
      bhalf8 k1 = *(const bhalf8*)&Kc[kr + (((q+4) ^ sw) * 8)];
      #pragma unroll
      for (int g = 0; g < 2; ++g){
        floatx4 s = {};
        s = MFMA16(k0, qf[g][0], s);
        s = MFMA16(k1, qf[g][1], s);
        union { uint2 u; bhalf4 h; } pu;
        pu.u = make_uint2(pk2(EXP2(s[0]), EXP2(s[1])),
                          pk2(EXP2(s[2]), EXP2(s[3])));
        pb[st][g] = pu.h;
      }
    }
    // PV transposed: A = V'^T[d][j'] (lane q,r16: d=dst*16+r16, j'=q*4+e),
    // read as b64 from Vls row d, j-chunk (st*2+(q>>1)) with XOR swizzle.
    #pragma unroll
    for (int dst = 0; dst < 4; ++dst){
      bhalf4 va[4];
      #pragma unroll
      for (int st = 0; st < 4; ++st){
        const int ch = (st*2 + (q >> 1)) ^ (r16 & 7);
        va[st] = *(const bhalf4*)&Vc[(dst*16 + r16)*64 + ch*8 + (q & 1)*4];
      }
      #pragma unroll
      for (int g = 0; g < 2; ++g)
        #pragma unroll
        for (int st = 0; st < 4; ++st)
          xaccT[g][dst] = MFMA4(va[st], pb[st][g], xaccT[g][dst]);
    }
    __builtin_amdgcn_s_setprio(0);
    __syncthreads();   // drains vmcnt: next buffer ready; LDS reads done
    cur ^= 1;
  }

  // epilogue: lane (q,r16): X[i=i0+wid*32+g*16+r16][d=dst*16+q*4+r], r=0..3
  #pragma unroll
  for (int g = 0; g < 2; ++g){
    const size_t irow = (size_t)(b*SEQ + i0 + wid*32 + g*16 + r16);
    #pragma unroll
    for (int dst = 0; dst < 4; ++dst){
      u32 w0 = (u32)f2b(xaccT[g][dst][0]) | ((u32)f2b(xaccT[g][dst][1]) << 16);
      u32 w1 = (u32)f2b(xaccT[g][dst][2]) | ((u32)f2b(xaccT[g][dst][3]) << 16);
      *(uint2*)&Xb[irow*DM + h*DK + dst*16 + q*4] = make_uint2(w0, w1);
    }
  }
}

// ---------------------------------------------------------------------------
extern "C" void kernel_launch(void* const* d_in, const int* in_sizes, int n_in,
                              void* d_out, int out_size, void* d_ws, size_t ws_size,
                              hipStream_t stream)
{
  const float* q  = (const float*)d_in[0];
  const float* k  = (const float*)d_in[1];
  const float* v  = (const float*)d_in[2];
  const float* Wq = (const float*)d_in[3];
  const float* bq = (const float*)d_in[4];
  const float* Wk = (const float*)d_in[5];
  const float* bk = (const float*)d_in[6];
  const float* Wv = (const float*)d_in[7];
  const float* bv = (const float*)d_in[8];
  const float* Wo = (const float*)d_in[9];
  const float* bo = (const float*)d_in[10];
  float* out = (float*)d_out;

  // ws: [Wtall 8M][Aq 8M (=Xb)][Ak 8M][Av 8M][Qb 8M][Kb 8M][Vt 8M] = 56 MiB
  char* ws = (char*)d_ws;
  const size_t WTB  = (size_t)DM * DM * sizeof(u16);    // 2 MiB
  const size_t TOKB = (size_t)NTOK * DM * sizeof(u16);  // 8 MiB
  u16* Wtall = (u16*)(ws);
  u16* Aq    = (u16*)(ws + 4*WTB);
  u16* Ak    = (u16*)(ws + 4*WTB + TOKB);
  u16* Av    = (u16*)(ws + 4*WTB + 2*TOKB);
  u16* Qb    = (u16*)(ws + 4*WTB + 3*TOKB);
  u16* Kb    = (u16*)(ws + 4*WTB + 4*TOKB);
  u16* Vt    = (u16*)(ws + 4*WTB + 5*TOKB);
  u16* Xb    = Aq;   // Aq consumed by gemm_qkv before pv writes Xb

  dim3 blk(256);
  cvt_qkv<<<dim3((NTOK*DM)/(256*8), 3), blk, 0, stream>>>(q, k, v, Aq, Ak, Av);
  wtrans4<<<dim3(16, 16, 4), blk, 0, stream>>>(Wq, Wk, Wv, Wo, Wtall);
  gemm_qkv<<<dim3(DM/128, NTOK/128, 3), blk, 0, stream>>>(
      Aq, Ak, Av, Wtall, bq, bk, bv, Qb, Kb, Vt);
  attn_stats<<<dim3(SEQ/64, NH*2), blk, 0, stream>>>(Qb, Kb, Vt);
  attn_pv<<<dim3(SEQ/128, NH*2), blk, 0, stream>>>(Qb, Kb, Vt, Xb);
  gemm_o<<<dim3(DM/128, NTOK/128), blk, 0, stream>>>(
      Xb, Wtall + 3*(size_t)DM*DM, bo, out);
}

// Round 18
// 263.305 us; speedup vs baseline: 1.0218x; 1.0218x over previous
//
#include <hip/hip_runtime.h>
#include <hip/hip_bf16.h>

#define SEQ   2048
#define NH    16
#define DK    64
#define DM    1024
#define NTOK  4096
#define C1    0.1803368801111204f   // 0.125 * log2(e)

typedef unsigned short u16;
typedef unsigned int   u32;
typedef short bhalf8 __attribute__((ext_vector_type(8)));   // 8 bf16 = 4 VGPRs
typedef float floatx4 __attribute__((ext_vector_type(4)));  // MFMA acc

#define MFMA16(a,b,c) __builtin_amdgcn_mfma_f32_16x16x32_bf16(a,b,c,0,0,0)

#if __has_builtin(__builtin_amdgcn_exp2f)
#define EXP2(x) __builtin_amdgcn_exp2f(x)
#else
#define EXP2(x) exp2f(x)
#endif

__device__ __forceinline__ u16 f2b(float f){
  union { float f; u32 u; } v; v.f = f;
  u32 r = v.u + 0x7fffu + ((v.u >> 16) & 1u);
  return (u16)(r >> 16);
}
__device__ __forceinline__ u32 pk2(float a, float b){
  union { __hip_bfloat162 h; u32 w; } o;
  o.h = __float22bfloat162_rn(make_float2(a, b));
  return o.w;
}
// async global->LDS, 16B/lane; lds ptr must be wave-uniform (HW adds lane*16)
__device__ __forceinline__ void gld_lds16(const u16* g, u16* lds){
  __builtin_amdgcn_global_load_lds(
      (const __attribute__((address_space(1))) u32*)g,
      (__attribute__((address_space(3))) u32*)lds, 16, 0, 0);
}

// ---------------------------------------------------------------------------
// Fused fp32->bf16 convert for q,k,v (memory-bound), 8 elems/thread
// ---------------------------------------------------------------------------
__global__ __launch_bounds__(256)
void cvt_qkv(const float* __restrict__ q, const float* __restrict__ k,
             const float* __restrict__ v, u16* __restrict__ Aq,
             u16* __restrict__ Ak, u16* __restrict__ Av)
{
  const float* in = (blockIdx.y == 0) ? q : (blockIdx.y == 1) ? k : v;
  u16* out       = (blockIdx.y == 0) ? Aq : (blockIdx.y == 1) ? Ak : Av;
  const size_t i = ((size_t)blockIdx.x * 256 + threadIdx.x) * 8;
  const float4 a = *(const float4*)(in + i);
  const float4 b = *(const float4*)(in + i + 4);
  uint4 o;
  o.x = pk2(a.x, a.y); o.y = pk2(a.z, a.w);
  o.z = pk2(b.x, b.y); o.w = pk2(b.z, b.w);
  *(uint4*)(out + i) = o;
}

// ---------------------------------------------------------------------------
// Fused transpose+convert: 4 weights fp32 [k][n] -> Wtall bf16 [z][n][k]
// ---------------------------------------------------------------------------
__global__ __launch_bounds__(256)
void wtrans4(const float* __restrict__ Wq, const float* __restrict__ Wk,
             const float* __restrict__ Wv, const float* __restrict__ Wo,
             u16* __restrict__ Wtall)
{
  __shared__ __align__(16) u16 T[64][68];
  const int z = blockIdx.z;
  const float* W = (z == 0) ? Wq : (z == 1) ? Wk : (z == 2) ? Wv : Wo;
  u16* Wt = Wtall + (size_t)z * DM * DM;
  const int k0 = blockIdx.y * 64, n0 = blockIdx.x * 64;
  const int t = threadIdx.x;
  #pragma unroll
  for (int p = 0; p < 16; ++p){
    int e = p*256 + t, k = e >> 6, n = e & 63;
    T[n][k] = f2b(W[(size_t)(k0+k)*DM + n0 + n]);
  }
  __syncthreads();
  #pragma unroll
  for (int p = 0; p < 8; ++p){
    int e = p*256 + t, n = e >> 5, kp = e & 31;
    u32 val = *(const u32*)&T[n][2*kp];
    *(u32*)&Wt[(size_t)(n0+n)*DM + k0 + 2*kp] = val;
  }
}

// ---------------------------------------------------------------------------
// Fused Q/K/V projection GEMM (m97 tile + XOR-swizzled LDS + 2-phase
// double-buffer: prefetch kc+32 issued before compute of kc, 1 barrier/iter).
// grid (DM/128, NTOK/128, 3); z picks A/W/bias/output.
// z=0: Qb = (q W + b)*C1 ; z=1: Kb ; z=2: Vt[((b*NH+h)*DK+d)*SEQ+s] (no scale)
// ---------------------------------------------------------------------------
__global__ __launch_bounds__(256)
void gemm_qkv(const u16* __restrict__ Aq, const u16* __restrict__ Ak,
              const u16* __restrict__ Av, const u16* __restrict__ Wtall,
              const float* __restrict__ bq, const float* __restrict__ bk,
              const float* __restrict__ bv, u16* __restrict__ Qb,
              u16* __restrict__ Kb, u16* __restrict__ Vt)
{
  __shared__ __align__(16) u16 Asm[2][128*32];   // [buf] rows of 64B, swizzled
  __shared__ __align__(16) u16 Bsm[2][128*32];
  const int z = blockIdx.z;
  const u16* A = (z == 0) ? Aq : (z == 1) ? Ak : Av;
  const u16* Wt = Wtall + (size_t)z * DM * DM;
  const float* bias = (z == 0) ? bq : (z == 1) ? bk : bv;
  const float cmul = (z == 0) ? C1 : 1.0f;

  const int bm = blockIdx.y * 128, bn = blockIdx.x * 128;
  const int t = threadIdx.x, wid = t >> 6, l = t & 63, r16 = l & 15, q = l >> 4;
  const int wm = (wid & 1) * 64, wn = (wid >> 1) * 64;
  // staging: lds slot = t (16B units); row = t>>2, slot-chunk = t&3,
  // global chunk g = (t&3) ^ (row&3)  (XOR swizzle)
  const int rL = t >> 2, gL = ((t & 3) ^ (rL & 3)) * 8;
  const u16* Ag = A  + (size_t)(bm + rL)*DM + gL;
  const u16* Bg = Wt + (size_t)(bn + rL)*DM + gL;
  const int wo = wid*512;
  const int sw = (r16 & 3);   // frag-read swizzle key
  floatx4 acc[4][4] = {};

  // prologue: stage kc=0 into buffer 0
  gld_lds16(Ag,                  Asm[0] + wo);
  gld_lds16(Ag + (size_t)64*DM,  Asm[0] + wo + 2048);
  gld_lds16(Bg,                  Bsm[0] + wo);
  gld_lds16(Bg + (size_t)64*DM,  Bsm[0] + wo + 2048);
  __syncthreads();

  int cur = 0;
  for (int kc = 0; kc < DM; kc += 32){
    if (kc + 32 < DM){
      const int nx = cur ^ 1;
      gld_lds16(Ag + kc + 32,                 Asm[nx] + wo);
      gld_lds16(Ag + kc + 32 + (size_t)64*DM, Asm[nx] + wo + 2048);
      gld_lds16(Bg + kc + 32,                 Bsm[nx] + wo);
      gld_lds16(Bg + kc + 32 + (size_t)64*DM, Bsm[nx] + wo + 2048);
    }
    __builtin_amdgcn_s_setprio(1);
    bhalf8 af[4], bf[4];
    #pragma unroll
    for (int i = 0; i < 4; ++i)
      af[i] = *(const bhalf8*)&Asm[cur][(wm + i*16 + r16)*32 + ((q ^ sw)*8)];
    #pragma unroll
    for (int j = 0; j < 4; ++j)
      bf[j] = *(const bhalf8*)&Bsm[cur][(wn + j*16 + r16)*32 + ((q ^ sw)*8)];
    #pragma unroll
    for (int i = 0; i < 4; ++i)
      #pragma unroll
      for (int j = 0; j < 4; ++j)
        acc[i][j] = MFMA16(af[i], bf[j], acc[i][j]);
    __builtin_amdgcn_s_setprio(0);
    __syncthreads();   // drains vmcnt: next buffer staged; frag reads done
    cur ^= 1;
  }

  if (z < 2){
    u16* C = (z == 0) ? Qb : Kb;
    #pragma unroll
    for (int j = 0; j < 4; ++j){
      const int n = bn + wn + j*16 + r16;
      const float bj = bias[n];
      #pragma unroll
      for (int i = 0; i < 4; ++i){
        const int m0 = bm + wm + i*16 + q*4;
        #pragma unroll
        for (int r = 0; r < 4; ++r)
          C[(size_t)(m0+r)*DM + n] = f2b((acc[i][j][r] + bj) * cmul);
      }
    }
  } else {
    const int h  = (bn + wn) >> 6;
    const int bb = (bm + wm) >> 11;
    const int s0 = (bm + wm) & (SEQ - 1);
    #pragma unroll
    for (int i = 0; i < 4; ++i){
      const int sl = s0 + i*16 + q*4;
      #pragma unroll
      for (int j = 0; j < 4; ++j){
        const int d = j*16 + r16;
        const float bj = bias[h*DK + d];
        u32 v0 = pk2(acc[i][j][0]+bj, acc[i][j][1]+bj);
        u32 v1 = pk2(acc[i][j][2]+bj, acc[i][j][3]+bj);
        *(uint2*)&Vt[((size_t)(bb*NH + h)*DK + d)*SEQ + sl] = make_uint2(v0, v1);
      }
    }
  }
}

// ---------------------------------------------------------------------------
// O-projection GEMM (same 2-phase double-buffered structure), bf16 -> fp32
// ---------------------------------------------------------------------------
__global__ __launch_bounds__(256)
void gemm_o(const u16* __restrict__ A, const u16* __restrict__ Wt,
            const float* __restrict__ bias, float* __restrict__ C)
{
  __shared__ __align__(16) u16 Asm[2][128*32];
  __shared__ __align__(16) u16 Bsm[2][128*32];
  const int bm = blockIdx.y * 128, bn = blockIdx.x * 128;
  const int t = threadIdx.x, wid = t >> 6, l = t & 63, r16 = l & 15, q = l >> 4;
  const int wm = (wid & 1) * 64, wn = (wid >> 1) * 64;
  const int rL = t >> 2, gL = ((t & 3) ^ (rL & 3)) * 8;
  const u16* Ag = A  + (size_t)(bm + rL)*DM + gL;
  const u16* Bg = Wt + (size_t)(bn + rL)*DM + gL;
  const int wo = wid*512;
  const int sw = (r16 & 3);
  floatx4 acc[4][4] = {};

  gld_lds16(Ag,                  Asm[0] + wo);
  gld_lds16(Ag + (size_t)64*DM,  Asm[0] + wo + 2048);
  gld_lds16(Bg,                  Bsm[0] + wo);
  gld_lds16(Bg + (size_t)64*DM,  Bsm[0] + wo + 2048);
  __syncthreads();

  int cur = 0;
  for (int kc = 0; kc < DM; kc += 32){
    if (kc + 32 < DM){
      const int nx = cur ^ 1;
      gld_lds16(Ag + kc + 32,                 Asm[nx] + wo);
      gld_lds16(Ag + kc + 32 + (size_t)64*DM, Asm[nx] + wo + 2048);
      gld_lds16(Bg + kc + 32,                 Bsm[nx] + wo);
      gld_lds16(Bg + kc + 32 + (size_t)64*DM, Bsm[nx] + wo + 2048);
    }
    __builtin_amdgcn_s_setprio(1);
    bhalf8 af[4], bf[4];
    #pragma unroll
    for (int i = 0; i < 4; ++i)
      af[i] = *(const bhalf8*)&Asm[cur][(wm + i*16 + r16)*32 + ((q ^ sw)*8)];
    #pragma unroll
    for (int j = 0; j < 4; ++j)
      bf[j] = *(const bhalf8*)&Bsm[cur][(wn + j*16 + r16)*32 + ((q ^ sw)*8)];
    #pragma unroll
    for (int i = 0; i < 4; ++i)
      #pragma unroll
      for (int j = 0; j < 4; ++j)
        acc[i][j] = MFMA16(af[i], bf[j], acc[i][j]);
    __builtin_amdgcn_s_setprio(0);
    __syncthreads();
    cur ^= 1;
  }
  #pragma unroll
  for (int j = 0; j < 4; ++j){
    const int n = bn + wn + j*16 + r16;
    const float bj = bias[n];
    #pragma unroll
    for (int i = 0; i < 4; ++i){
      const int m0 = bm + wm + i*16 + q*4;
      #pragma unroll
      for (int r = 0; r < 4; ++r)
        C[(size_t)(m0+r)*DM + n] = acc[i][j][r] + bj;
    }
  }
}

// ---------------------------------------------------------------------------
// Stats + fold: compute l_j = sum_i 2^(s'_ij) for its 64 j's, then scale
// Vt[bh][d][j] *= 1/l_j in place. Linv never touches global.
// ---------------------------------------------------------------------------
__global__ __launch_bounds__(256)
void attn_stats(const u16* __restrict__ Qb, const u16* __restrict__ Kb,
                u16* __restrict__ Vt)
{
  __shared__ float pl[4][64];
  __shared__ float sLinv[64];
  const int j0 = blockIdx.x * 64, bh = blockIdx.y, b = bh >> 4, h = bh & 15;
  const int t = threadIdx.x, wid = t >> 6, l = t & 63, r16 = l & 15, q = l >> 4;

  bhalf8 kf[4][2];
  const u16* kp = Kb + (size_t)(b*SEQ + j0 + r16)*DM + h*DK + q*8;
  #pragma unroll
  for (int st = 0; st < 4; ++st){
    kf[st][0] = *(const bhalf8*)(kp + (size_t)st*16*DM);
    kf[st][1] = *(const bhalf8*)(kp + (size_t)st*16*DM + 32);
  }
  float rl[4] = {0.f, 0.f, 0.f, 0.f};
  const u16* qp = Qb + (size_t)(b*SEQ + wid*16 + r16)*DM + h*DK + q*8;
  for (int it = 0; it < SEQ/64; ++it){
    bhalf8 qf0 = *(const bhalf8*)qp;
    bhalf8 qf1 = *(const bhalf8*)(qp + 32);
    qp += (size_t)64*DM;
    #pragma unroll
    for (int st = 0; st < 4; ++st){
      floatx4 s = {};
      s = MFMA16(qf0, kf[st][0], s);
      s = MFMA16(qf1, kf[st][1], s);
      rl[st] += EXP2(s[0]) + EXP2(s[1]) + EXP2(s[2]) + EXP2(s[3]);
    }
  }
  #pragma unroll
  for (int st = 0; st < 4; ++st){
    float v = rl[st];
    v += __shfl_xor(v, 16);
    v += __shfl_xor(v, 32);
    rl[st] = v;
  }
  if (q == 0){
    #pragma unroll
    for (int st = 0; st < 4; ++st) pl[wid][st*16 + r16] = rl[st];
  }
  __syncthreads();
  if (t < 64)
    sLinv[t] = 1.f / (pl[0][t] + pl[1][t] + pl[2][t] + pl[3][t]);
  __syncthreads();
  // scale Vt[bh][d][j0..j0+63] by sLinv[j-j0]; 16 elems/thread
  {
    const int d = t >> 2, cb = (t & 3) * 16;
    u16* vp = Vt + ((size_t)bh*DK + d)*SEQ + j0 + cb;
    uint4 w0 = *(uint4*)vp, w1 = *(uint4*)(vp + 8);
    float sc[16];
    #pragma unroll
    for (int e = 0; e < 16; ++e) sc[e] = sLinv[cb + e];
    #define SC2(w, s0, s1) pk2(__uint_as_float((w) << 16) * (s0), \
                               __uint_as_float((w) & 0xffff0000u) * (s1))
    w0.x = SC2(w0.x, sc[0],  sc[1]);  w0.y = SC2(w0.y, sc[2],  sc[3]);
    w0.z = SC2(w0.z, sc[4],  sc[5]);  w0.w = SC2(w0.w, sc[6],  sc[7]);
    w1.x = SC2(w1.x, sc[8],  sc[9]);  w1.y = SC2(w1.y, sc[10], sc[11]);
    w1.z = SC2(w1.z, sc[12], sc[13]); w1.w = SC2(w1.w, sc[14], sc[15]);
    #undef SC2
    *(uint4*)vp = w0; *(uint4*)(vp + 8) = w1;
  }
}

// ---------------------------------------------------------------------------
// PV: X[i][d] = sum_j 2^(s'_ij) * V'[j][d]  (V' pre-scaled by 1/l_j)
// i-tile 128. K/V double-buffered in LDS. In-register P with K=32 PV MFMAs:
// QK^T tile (h,s) row m computes j = h*32+(m>>2)*8+s*4+(m&3) (permuted
// per-lane K-row read), so the C-layout rows q*4+r land at j=h*32+q*8+s*4+r
// and tiles s=0,1 pack into the bhalf8 K=32 B-operand (k=(l>>4)*8+e) of the
// transposed PV: X^T[d][i] = sum V^T[d][j] P^T[j][i]. A = V^T b128 reads.
// No Pls, same MFMA (32/jt) and b128 (16/jt) counts as the proven R6 kernel.
// Kls staged with f_K(row)=(row&7)^(((row>>3)&1)<<2) to keep the permuted
// reads uniform 8-lanes/chunk (b128 minimum); Vls keeps f_V(row)=row&7.
// ---------------------------------------------------------------------------
__global__ __launch_bounds__(256)
void attn_pv(const u16* __restrict__ Qb, const u16* __restrict__ Kb,
             const u16* __restrict__ Vt, u16* __restrict__ Xb)
{
  __shared__ __align__(16) u16 Kls[2][64*64];    // [buf][j][d], f_K-swizzled
  __shared__ __align__(16) u16 Vls[2][64*64];    // [buf][d][s], f_V-swizzled
  const int i0 = blockIdx.x * 128, bh = blockIdx.y, b = bh >> 4, h = bh & 15;
  const int t = threadIdx.x, wid = t >> 6, l = t & 63, r16 = l & 15, q = l >> 4;

  // Q fragments: wave's 32 i-rows as 2 groups of 16 (direct global)
  bhalf8 qf[2][2];
  #pragma unroll
  for (int g = 0; g < 2; ++g){
    const u16* qp = Qb + (size_t)(b*SEQ + i0 + wid*32 + g*16 + r16)*DM + h*DK + q*8;
    qf[g][0] = *(const bhalf8*)qp;
    qf[g][1] = *(const bhalf8*)(qp + 32);
  }

  // gld staging: slot = call*256 + t; row = slot>>3, chunk c = slot&7,
  // K global chunk = c ^ f_K(row); V global chunk = c ^ (row&7)
  const int row0 = t >> 3, c0 = t & 7;
  const int fk0 = (row0 & 7) ^ (((row0 >> 3) & 1) << 2);
  const int row1 = row0 + 32;
  const int fk1 = (row1 & 7) ^ (((row1 >> 3) & 1) << 2);
  const int gk0 = (c0 ^ fk0) * 8;
  const int gk1 = (c0 ^ fk1) * 8;
  const int gv0 = (c0 ^ (row0 & 7)) * 8;
  const int gv1 = (c0 ^ (row1 & 7)) * 8;
  const u16* kp0 = Kb + (size_t)(b*SEQ + row0)*DM + h*DK + gk0;
  const u16* kp1 = Kb + (size_t)(b*SEQ + row1)*DM + h*DK + gk1;
  const u16* vp0 = Vt + ((size_t)bh*DK + row0)*SEQ + gv0;
  const u16* vp1 = Vt + ((size_t)bh*DK + row1)*SEQ + gv1;
  const int wo = wid*512;
  const int swv = (r16 & 7);   // V frag-read swizzle key

  floatx4 xaccT[2][4] = {};    // [g][dst]: X^T[d=dst*16+q*4+r][i=r16]

  // prologue: stage jt=0 into buffer 0
  gld_lds16(kp0, &Kls[0][wo]);
  gld_lds16(kp1, &Kls[0][wo + 2048]);
  gld_lds16(vp0, &Vls[0][wo]);
  gld_lds16(vp1, &Vls[0][wo + 2048]);
  __syncthreads();

  int cur = 0;
  for (int jt = 0; jt < SEQ/64; ++jt){
    // prefetch jt+1 into the other buffer; latency hidden under compute.
    if (jt + 1 < SEQ/64){
      const int nx = cur ^ 1;
      gld_lds16(kp0 + (size_t)(jt+1)*64*DM, &Kls[nx][wo]);
      gld_lds16(kp1 + (size_t)(jt+1)*64*DM, &Kls[nx][wo + 2048]);
      gld_lds16(vp0 + (jt+1)*64,            &Vls[nx][wo]);
      gld_lds16(vp1 + (jt+1)*64,            &Vls[nx][wo + 2048]);
    }
    const u16* Kc = &Kls[cur][0];
    const u16* Vc = &Vls[cur][0];

    __builtin_amdgcn_s_setprio(1);
    #pragma unroll
    for (int h2 = 0; h2 < 2; ++h2){
      // QK^T for this 32-j half: tiles s=0,1 with permuted j-rows.
      // Lane's A-row m=r16 reads K row jrow; C rows q*4+r = j h2*32+q*8+s*4+r.
      floatx4 sacc[2][2];   // [s][g]
      #pragma unroll
      for (int s = 0; s < 2; ++s){
        const int jrow = h2*32 + (r16 >> 2)*8 + s*4 + (r16 & 3);
        const int swr  = (jrow & 7) ^ (((jrow >> 3) & 1) << 2);
        const int kr   = jrow * 64;
        bhalf8 k0 = *(const bhalf8*)&Kc[kr + ((q     ^ swr) * 8)];
        bhalf8 k1 = *(const bhalf8*)&Kc[kr + (((q+4) ^ swr) * 8)];
        #pragma unroll
        for (int g = 0; g < 2; ++g){
          floatx4 s0 = {};
          s0 = MFMA16(k0, qf[g][0], s0);
          s0 = MFMA16(k1, qf[g][1], s0);
          sacc[s][g] = s0;
        }
      }
      // pack P: bhalf8 element e = exp2(S^T[j=h2*32+q*8+e][i]),
      // e<4 from s=0 acc[e], e>=4 from s=1 acc[e-4]
      bhalf8 pb[2];
      #pragma unroll
      for (int g = 0; g < 2; ++g){
        u32 w0 = pk2(EXP2(sacc[0][g][0]), EXP2(sacc[0][g][1]));
        u32 w1 = pk2(EXP2(sacc[0][g][2]), EXP2(sacc[0][g][3]));
        u32 w2 = pk2(EXP2(sacc[1][g][0]), EXP2(sacc[1][g][1]));
        u32 w3 = pk2(EXP2(sacc[1][g][2]), EXP2(sacc[1][g][3]));
        union { uint4 u; bhalf8 hh; } pu;
        pu.u = make_uint4(w0, w1, w2, w3);
        pb[g] = pu.hh;
      }
      // PV transposed, K=32: A = V^T[d=dst*16+r16][j=h2*32+q*8+e] (b128,
      // logical chunk h2*4+q de-swizzled via swv), B = pb (in-register P).
      #pragma unroll
      for (int dst = 0; dst < 4; ++dst){
        bhalf8 va = *(const bhalf8*)
            &Vc[(dst*16 + r16)*64 + (((h2*4 + q) ^ swv) * 8)];
        #pragma unroll
        for (int g = 0; g < 2; ++g)
          xaccT[g][dst] = MFMA16(va, pb[g], xaccT[g][dst]);
      }
    }
    __builtin_amdgcn_s_setprio(0);
    __syncthreads();   // drains vmcnt: next buffer ready; LDS reads done
    cur ^= 1;
  }

  // epilogue: lane (q,r16): X[i=i0+wid*32+g*16+r16][d=dst*16+q*4+r], r=0..3
  #pragma unroll
  for (int g = 0; g < 2; ++g){
    const size_t irow = (size_t)(b*SEQ + i0 + wid*32 + g*16 + r16);
    #pragma unroll
    for (int dst = 0; dst < 4; ++dst){
      u32 w0 = (u32)f2b(xaccT[g][dst][0]) | ((u32)f2b(xaccT[g][dst][1]) << 16);
      u32 w1 = (u32)f2b(xaccT[g][dst][2]) | ((u32)f2b(xaccT[g][dst][3]) << 16);
      *(uint2*)&Xb[irow*DM + h*DK + dst*16 + q*4] = make_uint2(w0, w1);
    }
  }
}

// ---------------------------------------------------------------------------
extern "C" void kernel_launch(void* const* d_in, const int* in_sizes, int n_in,
                              void* d_out, int out_size, void* d_ws, size_t ws_size,
                              hipStream_t stream)
{
  const float* q  = (const float*)d_in[0];
  const float* k  = (const float*)d_in[1];
  const float* v  = (const float*)d_in[2];
  const float* Wq = (const float*)d_in[3];
  const float* bq = (const float*)d_in[4];
  const float* Wk = (const float*)d_in[5];
  const float* bk = (const float*)d_in[6];
  const float* Wv = (const float*)d_in[7];
  const float* bv = (const float*)d_in[8];
  const float* Wo = (const float*)d_in[9];
  const float* bo = (const float*)d_in[10];
  float* out = (float*)d_out;

  // ws: [Wtall 8M][Aq 8M (=Xb)][Ak 8M][Av 8M][Qb 8M][Kb 8M][Vt 8M] = 56 MiB
  char* ws = (char*)d_ws;
  const size_t WTB  = (size_t)DM * DM * sizeof(u16);    // 2 MiB
  const size_t TOKB = (size_t)NTOK * DM * sizeof(u16);  // 8 MiB
  u16* Wtall = (u16*)(ws);
  u16* Aq    = (u16*)(ws + 4*WTB);
  u16* Ak    = (u16*)(ws + 4*WTB + TOKB);
  u16* Av    = (u16*)(ws + 4*WTB + 2*TOKB);
  u16* Qb    = (u16*)(ws + 4*WTB + 3*TOKB);
  u16* Kb    = (u16*)(ws + 4*WTB + 4*TOKB);
  u16* Vt    = (u16*)(ws + 4*WTB + 5*TOKB);
  u16* Xb    = Aq;   // Aq consumed by gemm_qkv before pv writes Xb

  dim3 blk(256);
  cvt_qkv<<<dim3((NTOK*DM)/(256*8), 3), blk, 0, stream>>>(q, k, v, Aq, Ak, Av);
  wtrans4<<<dim3(16, 16, 4), blk, 0, stream>>>(Wq, Wk, Wv, Wo, Wtall);
  gemm_qkv<<<dim3(DM/128, NTOK/128, 3), blk, 0, stream>>>(
      Aq, Ak, Av, Wtall, bq, bk, bv, Qb, Kb, Vt);
  attn_stats<<<dim3(SEQ/64, NH*2), blk, 0, stream>>>(Qb, Kb, Vt);
  attn_pv<<<dim3(SEQ/128, NH*2), blk, 0, stream>>>(Qb, Kb, Vt, Xb);
  gemm_o<<<dim3(DM/128, NTOK/128), blk, 0, stream>>>(
      Xb, Wtall + 3*(size_t)DM*DM, bo, out);
}

// Round 21
// 260.173 us; speedup vs baseline: 1.0341x; 1.0120x over previous
//
#include <hip/hip_runtime.h>
#include <hip/hip_bf16.h>

#define SEQ   2048
#define NH    16
#define DK    64
#define DM    1024
#define NTOK  4096
#define C1    0.1803368801111204f   // 0.125 * log2(e)

typedef unsigned short u16;
typedef unsigned int   u32;
typedef short bhalf8 __attribute__((ext_vector_type(8)));   // 8 bf16 = 4 VGPRs
typedef float floatx4 __attribute__((ext_vector_type(4)));  // MFMA acc

#define MFMA16(a,b,c) __builtin_amdgcn_mfma_f32_16x16x32_bf16(a,b,c,0,0,0)

#if __has_builtin(__builtin_amdgcn_exp2f)
#define EXP2(x) __builtin_amdgcn_exp2f(x)
#else
#define EXP2(x) exp2f(x)
#endif

__device__ __forceinline__ u16 f2b(float f){
  union { float f; u32 u; } v; v.f = f;
  u32 r = v.u + 0x7fffu + ((v.u >> 16) & 1u);
  return (u16)(r >> 16);
}
__device__ __forceinline__ u32 pk2(float a, float b){
  union { __hip_bfloat162 h; u32 w; } o;
  o.h = __float22bfloat162_rn(make_float2(a, b));
  return o.w;
}
// async global->LDS, 16B/lane; lds ptr must be wave-uniform (HW adds lane*16)
__device__ __forceinline__ void gld_lds16(const u16* g, u16* lds){
  __builtin_amdgcn_global_load_lds(
      (const __attribute__((address_space(1))) u32*)g,
      (__attribute__((address_space(3))) u32*)lds, 16, 0, 0);
}

// ---------------------------------------------------------------------------
// Fused fp32->bf16 convert for q,k,v (memory-bound), 8 elems/thread
// ---------------------------------------------------------------------------
__global__ __launch_bounds__(256)
void cvt_qkv(const float* __restrict__ q, const float* __restrict__ k,
             const float* __restrict__ v, u16* __restrict__ Aq,
             u16* __restrict__ Ak, u16* __restrict__ Av)
{
  const float* in = (blockIdx.y == 0) ? q : (blockIdx.y == 1) ? k : v;
  u16* out       = (blockIdx.y == 0) ? Aq : (blockIdx.y == 1) ? Ak : Av;
  const size_t i = ((size_t)blockIdx.x * 256 + threadIdx.x) * 8;
  const float4 a = *(const float4*)(in + i);
  const float4 b = *(const float4*)(in + i + 4);
  uint4 o;
  o.x = pk2(a.x, a.y); o.y = pk2(a.z, a.w);
  o.z = pk2(b.x, b.y); o.w = pk2(b.z, b.w);
  *(uint4*)(out + i) = o;
}

// ---------------------------------------------------------------------------
// Fused transpose+convert: 4 weights fp32 [k][n] -> Wtall bf16 [z][n][k]
// ---------------------------------------------------------------------------
__global__ __launch_bounds__(256)
void wtrans4(const float* __restrict__ Wq, const float* __restrict__ Wk,
             const float* __restrict__ Wv, const float* __restrict__ Wo,
             u16* __restrict__ Wtall)
{
  __shared__ __align__(16) u16 T[64][68];
  const int z = blockIdx.z;
  const float* W = (z == 0) ? Wq : (z == 1) ? Wk : (z == 2) ? Wv : Wo;
  u16* Wt = Wtall + (size_t)z * DM * DM;
  const int k0 = blockIdx.y * 64, n0 = blockIdx.x * 64;
  const int t = threadIdx.x;
  #pragma unroll
  for (int p = 0; p < 16; ++p){
    int e = p*256 + t, k = e >> 6, n = e & 63;
    T[n][k] = f2b(W[(size_t)(k0+k)*DM + n0 + n]);
  }
  __syncthreads();
  #pragma unroll
  for (int p = 0; p < 8; ++p){
    int e = p*256 + t, n = e >> 5, kp = e & 31;
    u32 val = *(const u32*)&T[n][2*kp];
    *(u32*)&Wt[(size_t)(n0+n)*DM + k0 + 2*kp] = val;
  }
}

// ---------------------------------------------------------------------------
// Fused Q/K/V projection GEMM (m97 tile + XOR-swizzled LDS + 2-phase
// double-buffer: prefetch kc+32 issued before compute of kc, 1 barrier/iter).
// grid (DM/128, NTOK/128, 3); z picks A/W/bias/output.
// z=0: Qb = (q W + b)*C1 ; z=1: Kb ; z=2: Vt[((b*NH+h)*DK+d)*SEQ+s] (no scale)
// ---------------------------------------------------------------------------
__global__ __launch_bounds__(256)
void gemm_qkv(const u16* __restrict__ Aq, const u16* __restrict__ Ak,
              const u16* __restrict__ Av, const u16* __restrict__ Wtall,
              const float* __restrict__ bq, const float* __restrict__ bk,
              const float* __restrict__ bv, u16* __restrict__ Qb,
              u16* __restrict__ Kb, u16* __restrict__ Vt)
{
  __shared__ __align__(16) u16 Asm[2][128*32];   // [buf] rows of 64B, swizzled
  __shared__ __align__(16) u16 Bsm[2][128*32];
  const int z = blockIdx.z;
  const u16* A = (z == 0) ? Aq : (z == 1) ? Ak : Av;
  const u16* Wt = Wtall + (size_t)z * DM * DM;
  const float* bias = (z == 0) ? bq : (z == 1) ? bk : bv;
  const float cmul = (z == 0) ? C1 : 1.0f;

  const int bm = blockIdx.y * 128, bn = blockIdx.x * 128;
  const int t = threadIdx.x, wid = t >> 6, l = t & 63, r16 = l & 15, q = l >> 4;
  const int wm = (wid & 1) * 64, wn = (wid >> 1) * 64;
  // staging: lds slot = t (16B units); row = t>>2, slot-chunk = t&3,
  // global chunk g = (t&3) ^ (row&3)  (XOR swizzle)
  const int rL = t >> 2, gL = ((t & 3) ^ (rL & 3)) * 8;
  const u16* Ag = A  + (size_t)(bm + rL)*DM + gL;
  const u16* Bg = Wt + (size_t)(bn + rL)*DM + gL;
  const int wo = wid*512;
  const int sw = (r16 & 3);   // frag-read swizzle key
  floatx4 acc[4][4] = {};

  // prologue: stage kc=0 into buffer 0
  gld_lds16(Ag,                  Asm[0] + wo);
  gld_lds16(Ag + (size_t)64*DM,  Asm[0] + wo + 2048);
  gld_lds16(Bg,                  Bsm[0] + wo);
  gld_lds16(Bg + (size_t)64*DM,  Bsm[0] + wo + 2048);
  __syncthreads();

  int cur = 0;
  for (int kc = 0; kc < DM; kc += 32){
    if (kc + 32 < DM){
      const int nx = cur ^ 1;
      gld_lds16(Ag + kc + 32,                 Asm[nx] + wo);
      gld_lds16(Ag + kc + 32 + (size_t)64*DM, Asm[nx] + wo + 2048);
      gld_lds16(Bg + kc + 32,                 Bsm[nx] + wo);
      gld_lds16(Bg + kc + 32 + (size_t)64*DM, Bsm[nx] + wo + 2048);
    }
    __builtin_amdgcn_s_setprio(1);
    bhalf8 af[4], bf[4];
    #pragma unroll
    for (int i = 0; i < 4; ++i)
      af[i] = *(const bhalf8*)&Asm[cur][(wm + i*16 + r16)*32 + ((q ^ sw)*8)];
    #pragma unroll
    for (int j = 0; j < 4; ++j)
      bf[j] = *(const bhalf8*)&Bsm[cur][(wn + j*16 + r16)*32 + ((q ^ sw)*8)];
    #pragma unroll
    for (int i = 0; i < 4; ++i)
      #pragma unroll
      for (int j = 0; j < 4; ++j)
        acc[i][j] = MFMA16(af[i], bf[j], acc[i][j]);
    __builtin_amdgcn_s_setprio(0);
    __syncthreads();   // drains vmcnt: next buffer staged; frag reads done
    cur ^= 1;
  }

  if (z < 2){
    u16* C = (z == 0) ? Qb : Kb;
    #pragma unroll
    for (int j = 0; j < 4; ++j){
      const int n = bn + wn + j*16 + r16;
      const float bj = bias[n];
      #pragma unroll
      for (int i = 0; i < 4; ++i){
        const int m0 = bm + wm + i*16 + q*4;
        #pragma unroll
        for (int r = 0; r < 4; ++r)
          C[(size_t)(m0+r)*DM + n] = f2b((acc[i][j][r] + bj) * cmul);
      }
    }
  } else {
    const int h  = (bn + wn) >> 6;
    const int bb = (bm + wm) >> 11;
    const int s0 = (bm + wm) & (SEQ - 1);
    #pragma unroll
    for (int i = 0; i < 4; ++i){
      const int sl = s0 + i*16 + q*4;
      #pragma unroll
      for (int j = 0; j < 4; ++j){
        const int d = j*16 + r16;
        const float bj = bias[h*DK + d];
        u32 v0 = pk2(acc[i][j][0]+bj, acc[i][j][1]+bj);
        u32 v1 = pk2(acc[i][j][2]+bj, acc[i][j][3]+bj);
        *(uint2*)&Vt[((size_t)(bb*NH + h)*DK + d)*SEQ + sl] = make_uint2(v0, v1);
      }
    }
  }
}

// ---------------------------------------------------------------------------
// O-projection GEMM (same 2-phase double-buffered structure), bf16 -> fp32
// ---------------------------------------------------------------------------
__global__ __launch_bounds__(256)
void gemm_o(const u16* __restrict__ A, const u16* __restrict__ Wt,
            const float* __restrict__ bias, float* __restrict__ C)
{
  __shared__ __align__(16) u16 Asm[2][128*32];
  __shared__ __align__(16) u16 Bsm[2][128*32];
  const int bm = blockIdx.y * 128, bn = blockIdx.x * 128;
  const int t = threadIdx.x, wid = t >> 6, l = t & 63, r16 = l & 15, q = l >> 4;
  const int wm = (wid & 1) * 64, wn = (wid >> 1) * 64;
  const int rL = t >> 2, gL = ((t & 3) ^ (rL & 3)) * 8;
  const u16* Ag = A  + (size_t)(bm + rL)*DM + gL;
  const u16* Bg = Wt + (size_t)(bn + rL)*DM + gL;
  const int wo = wid*512;
  const int sw = (r16 & 3);
  floatx4 acc[4][4] = {};

  gld_lds16(Ag,                  Asm[0] + wo);
  gld_lds16(Ag + (size_t)64*DM,  Asm[0] + wo + 2048);
  gld_lds16(Bg,                  Bsm[0] + wo);
  gld_lds16(Bg + (size_t)64*DM,  Bsm[0] + wo + 2048);
  __syncthreads();

  int cur = 0;
  for (int kc = 0; kc < DM; kc += 32){
    if (kc + 32 < DM){
      const int nx = cur ^ 1;
      gld_lds16(Ag + kc + 32,                 Asm[nx] + wo);
      gld_lds16(Ag + kc + 32 + (size_t)64*DM, Asm[nx] + wo + 2048);
      gld_lds16(Bg + kc + 32,                 Bsm[nx] + wo);
      gld_lds16(Bg + kc + 32 + (size_t)64*DM, Bsm[nx] + wo + 2048);
    }
    __builtin_amdgcn_s_setprio(1);
    bhalf8 af[4], bf[4];
    #pragma unroll
    for (int i = 0; i < 4; ++i)
      af[i] = *(const bhalf8*)&Asm[cur][(wm + i*16 + r16)*32 + ((q ^ sw)*8)];
    #pragma unroll
    for (int j = 0; j < 4; ++j)
      bf[j] = *(const bhalf8*)&Bsm[cur][(wn + j*16 + r16)*32 + ((q ^ sw)*8)];
    #pragma unroll
    for (int i = 0; i < 4; ++i)
      #pragma unroll
      for (int j = 0; j < 4; ++j)
        acc[i][j] = MFMA16(af[i], bf[j], acc[i][j]);
    __builtin_amdgcn_s_setprio(0);
    __syncthreads();
    cur ^= 1;
  }
  #pragma unroll
  for (int j = 0; j < 4; ++j){
    const int n = bn + wn + j*16 + r16;
    const float bj = bias[n];
    #pragma unroll
    for (int i = 0; i < 4; ++i){
      const int m0 = bm + wm + i*16 + q*4;
      #pragma unroll
      for (int r = 0; r < 4; ++r)
        C[(size_t)(m0+r)*DM + n] = acc[i][j][r] + bj;
    }
  }
}

// ---------------------------------------------------------------------------
// Stats + fold: compute l_j = sum_i 2^(s'_ij) for its 64 j's, then scale
// Vt[bh][d][j] *= 1/l_j in place. Linv never touches global.
// ---------------------------------------------------------------------------
__global__ __launch_bounds__(256)
void attn_stats(const u16* __restrict__ Qb, const u16* __restrict__ Kb,
                u16* __restrict__ Vt)
{
  __shared__ float pl[4][64];
  __shared__ float sLinv[64];
  const int j0 = blockIdx.x * 64, bh = blockIdx.y, b = bh >> 4, h = bh & 15;
  const int t = threadIdx.x, wid = t >> 6, l = t & 63, r16 = l & 15, q = l >> 4;

  bhalf8 kf[4][2];
  const u16* kp = Kb + (size_t)(b*SEQ + j0 + r16)*DM + h*DK + q*8;
  #pragma unroll
  for (int st = 0; st < 4; ++st){
    kf[st][0] = *(const bhalf8*)(kp + (size_t)st*16*DM);
    kf[st][1] = *(const bhalf8*)(kp + (size_t)st*16*DM + 32);
  }
  float rl[4] = {0.f, 0.f, 0.f, 0.f};
  const u16* qp = Qb + (size_t)(b*SEQ + wid*16 + r16)*DM + h*DK + q*8;
  for (int it = 0; it < SEQ/64; ++it){
    bhalf8 qf0 = *(const bhalf8*)qp;
    bhalf8 qf1 = *(const bhalf8*)(qp + 32);
    qp += (size_t)64*DM;
    #pragma unroll
    for (int st = 0; st < 4; ++st){
      floatx4 s = {};
      s = MFMA16(qf0, kf[st][0], s);
      s = MFMA16(qf1, kf[st][1], s);
      rl[st] += EXP2(s[0]) + EXP2(s[1]) + EXP2(s[2]) + EXP2(s[3]);
    }
  }
  #pragma unroll
  for (int st = 0; st < 4; ++st){
    float v = rl[st];
    v += __shfl_xor(v, 16);
    v += __shfl_xor(v, 32);
    rl[st] = v;
  }
  if (q == 0){
    #pragma unroll
    for (int st = 0; st < 4; ++st) pl[wid][st*16 + r16] = rl[st];
  }
  __syncthreads();
  if (t < 64)
    sLinv[t] = 1.f / (pl[0][t] + pl[1][t] + pl[2][t] + pl[3][t]);
  __syncthreads();
  // scale Vt[bh][d][j0..j0+63] by sLinv[j-j0]; 16 elems/thread
  {
    const int d = t >> 2, cb = (t & 3) * 16;
    u16* vp = Vt + ((size_t)bh*DK + d)*SEQ + j0 + cb;
    uint4 w0 = *(uint4*)vp, w1 = *(uint4*)(vp + 8);
    float sc[16];
    #pragma unroll
    for (int e = 0; e < 16; ++e) sc[e] = sLinv[cb + e];
    #define SC2(w, s0, s1) pk2(__uint_as_float((w) << 16) * (s0), \
                               __uint_as_float((w) & 0xffff0000u) * (s1))
    w0.x = SC2(w0.x, sc[0],  sc[1]);  w0.y = SC2(w0.y, sc[2],  sc[3]);
    w0.z = SC2(w0.z, sc[4],  sc[5]);  w0.w = SC2(w0.w, sc[6],  sc[7]);
    w1.x = SC2(w1.x, sc[8],  sc[9]);  w1.y = SC2(w1.y, sc[10], sc[11]);
    w1.z = SC2(w1.z, sc[12], sc[13]); w1.w = SC2(w1.w, sc[14], sc[15]);
    #undef SC2
    *(uint4*)vp = w0; *(uint4*)(vp + 8) = w1;
  }
}

// ---------------------------------------------------------------------------
// PV: X[i][d] = sum_j 2^(s'_ij) * V'[j][d]  (V' pre-scaled by 1/l_j)
// 512 threads / 8 waves; each wave owns 16 i-rows (i-tile still 128).
// Same total MFMA/exp2/staging per block as the 4-wave version, but 2x the
// waves per CU (occupancy cap 25%->50%) to hide dependency chains and the
// per-iter barrier. In-register P (conflicts=0, verified R18): permuted-j
// QK^T rows feed the K=32 PV B-operand directly. K/V offsets hoisted
// (jt-invariant). Staging: one 64-row gld call each for K and V per jt.
// ---------------------------------------------------------------------------
__global__ __launch_bounds__(512)
void attn_pv(const u16* __restrict__ Qb, const u16* __restrict__ Kb,
             const u16* __restrict__ Vt, u16* __restrict__ Xb)
{
  __shared__ __align__(16) u16 Kls[2][64*64];    // [buf][j][d], f_K-swizzled
  __shared__ __align__(16) u16 Vls[2][64*64];    // [buf][d][s], f_V-swizzled
  const int i0 = blockIdx.x * 128, bh = blockIdx.y, b = bh >> 4, h = bh & 15;
  const int t = threadIdx.x, wid = t >> 6, l = t & 63, r16 = l & 15, q = l >> 4;

  // Q fragments: wave's 16 i-rows (direct global)
  bhalf8 qf0, qf1;
  {
    const u16* qp = Qb + (size_t)(b*SEQ + i0 + wid*16 + r16)*DM + h*DK + q*8;
    qf0 = *(const bhalf8*)qp;
    qf1 = *(const bhalf8*)(qp + 32);
  }

  // gld staging: slot = t (512 lanes cover 64 rows x 8 chunks); row = t>>3,
  // chunk c = t&7; K global chunk = c ^ f_K(row); V global chunk = c ^ (row&7)
  const int row = t >> 3, c0 = t & 7;
  const int fk = (row & 7) ^ (((row >> 3) & 1) << 2);
  const int gk = (c0 ^ fk) * 8;
  const int gv = (c0 ^ (row & 7)) * 8;
  const u16* kp = Kb + (size_t)(b*SEQ + row)*DM + h*DK + gk;
  const u16* vp = Vt + ((size_t)bh*DK + row)*SEQ + gv;
  const int wo = wid*512;     // u16 units; 8 waves x 512 = full 64x64 tile
  const int swv = (r16 & 7);  // V frag-read swizzle key

  // jt-invariant LDS read offsets (u16 units)
  int koff[2][2][2], voff[2][4];
  #pragma unroll
  for (int h2 = 0; h2 < 2; ++h2){
    #pragma unroll
    for (int s = 0; s < 2; ++s){
      const int jrow = h2*32 + (r16 >> 2)*8 + s*4 + (r16 & 3);
      const int swr  = (jrow & 7) ^ (((jrow >> 3) & 1) << 2);
      koff[h2][s][0] = jrow*64 + ((q     ^ swr) * 8);
      koff[h2][s][1] = jrow*64 + (((q+4) ^ swr) * 8);
    }
    #pragma unroll
    for (int dst = 0; dst < 4; ++dst)
      voff[h2][dst] = (dst*16 + r16)*64 + (((h2*4 + q) ^ swv) * 8);
  }

  floatx4 xaccT[4] = {};   // [dst]: X^T[d=dst*16+q*4+r][i=r16]

  // prologue: stage jt=0 into buffer 0
  gld_lds16(kp, &Kls[0][wo]);
  gld_lds16(vp, &Vls[0][wo]);
  __syncthreads();

  int cur = 0;
  for (int jt = 0; jt < SEQ/64; ++jt){
    // prefetch jt+1 into the other buffer; latency hidden under compute.
    if (jt + 1 < SEQ/64){
      const int nx = cur ^ 1;
      gld_lds16(kp + (size_t)(jt+1)*64*DM, &Kls[nx][wo]);
      gld_lds16(vp + (jt+1)*64,            &Vls[nx][wo]);
    }
    const u16* Kc = &Kls[cur][0];
    const u16* Vc = &Vls[cur][0];

    __builtin_amdgcn_s_setprio(1);
    #pragma unroll
    for (int h2 = 0; h2 < 2; ++h2){
      // QK^T for this 32-j half: tiles s=0,1 with permuted j-rows;
      // C rows q*4+r = j h2*32+q*8+s*4+r.
      floatx4 sacc[2];
      #pragma unroll
      for (int s = 0; s < 2; ++s){
        bhalf8 k0 = *(const bhalf8*)&Kc[koff[h2][s][0]];
        bhalf8 k1 = *(const bhalf8*)&Kc[koff[h2][s][1]];
        floatx4 s0 = {};
        s0 = MFMA16(k0, qf0, s0);
        s0 = MFMA16(k1, qf1, s0);
        sacc[s] = s0;
      }
      // pack P: bhalf8 elem e = exp2(S^T[j=h2*32+q*8+e][i]); e<4 from s=0
      union { uint4 u; bhalf8 hh; } pu;
      pu.u = make_uint4(pk2(EXP2(sacc[0][0]), EXP2(sacc[0][1])),
                        pk2(EXP2(sacc[0][2]), EXP2(sacc[0][3])),
                        pk2(EXP2(sacc[1][0]), EXP2(sacc[1][1])),
                        pk2(EXP2(sacc[1][2]), EXP2(sacc[1][3])));
      const bhalf8 pb = pu.hh;
      // PV transposed, K=32: A = V^T[d=dst*16+r16][j=h2*32+q*8+e] (b128),
      // B = pb (in-register P).
      #pragma unroll
      for (int dst = 0; dst < 4; ++dst){
        bhalf8 va = *(const bhalf8*)&Vc[voff[h2][dst]];
        xaccT[dst] = MFMA16(va, pb, xaccT[dst]);
      }
    }
    __builtin_amdgcn_s_setprio(0);
    __syncthreads();   // drains vmcnt: next buffer ready; LDS reads done
    cur ^= 1;
  }

  // epilogue: lane (q,r16): X[i=i0+wid*16+r16][d=dst*16+q*4+r], r=0..3
  {
    const size_t irow = (size_t)(b*SEQ + i0 + wid*16 + r16);
    #pragma unroll
    for (int dst = 0; dst < 4; ++dst){
      u32 w0 = (u32)f2b(xaccT[dst][0]) | ((u32)f2b(xaccT[dst][1]) << 16);
      u32 w1 = (u32)f2b(xaccT[dst][2]) | ((u32)f2b(xaccT[dst][3]) << 16);
      *(uint2*)&Xb[irow*DM + h*DK + dst*16 + q*4] = make_uint2(w0, w1);
    }
  }
}

// ---------------------------------------------------------------------------
extern "C" void kernel_launch(void* const* d_in, const int* in_sizes, int n_in,
                              void* d_out, int out_size, void* d_ws, size_t ws_size,
                              hipStream_t stream)
{
  const float* q  = (const float*)d_in[0];
  const float* k  = (const float*)d_in[1];
  const float* v  = (const float*)d_in[2];
  const float* Wq = (const float*)d_in[3];
  const float* bq = (const float*)d_in[4];
  const float* Wk = (const float*)d_in[5];
  const float* bk = (const float*)d_in[6];
  const float* Wv = (const float*)d_in[7];
  const float* bv = (const float*)d_in[8];
  const float* Wo = (const float*)d_in[9];
  const float* bo = (const float*)d_in[10];
  float* out = (float*)d_out;

  // ws: [Wtall 8M][Aq 8M (=Xb)][Ak 8M][Av 8M][Qb 8M][Kb 8M][Vt 8M] = 56 MiB
  char* ws = (char*)d_ws;
  const size_t WTB  = (size_t)DM * DM * sizeof(u16);    // 2 MiB
  const size_t TOKB = (size_t)NTOK * DM * sizeof(u16);  // 8 MiB
  u16* Wtall = (u16*)(ws);
  u16* Aq    = (u16*)(ws + 4*WTB);
  u16* Ak    = (u16*)(ws + 4*WTB + TOKB);
  u16* Av    = (u16*)(ws + 4*WTB + 2*TOKB);
  u16* Qb    = (u16*)(ws + 4*WTB + 3*TOKB);
  u16* Kb    = (u16*)(ws + 4*WTB + 4*TOKB);
  u16* Vt    = (u16*)(ws + 4*WTB + 5*TOKB);
  u16* Xb    = Aq;   // Aq consumed by gemm_qkv before pv writes Xb

  dim3 blk(256);
  dim3 blk512(512);
  cvt_qkv<<<dim3((NTOK*DM)/(256*8), 3), blk, 0, stream>>>(q, k, v, Aq, Ak, Av);
  wtrans4<<<dim3(16, 16, 4), blk, 0, stream>>>(Wq, Wk, Wv, Wo, Wtall);
  gemm_qkv<<<dim3(DM/128, NTOK/128, 3), blk, 0, stream>>>(
      Aq, Ak, Av, Wtall, bq, bk, bv, Qb, Kb, Vt);
  attn_stats<<<dim3(SEQ/64, NH*2), blk, 0, stream>>>(Qb, Kb, Vt);
  attn_pv<<<dim3(SEQ/128, NH*2), blk512, 0, stream>>>(Qb, Kb, Vt, Xb);
  gemm_o<<<dim3(DM/128, NTOK/128), blk, 0, stream>>>(
      Xb, Wtall + 3*(size_t)DM*DM, bo, out);
}